// Round 3
// baseline (70.428 us; speedup 1.0000x reference)
//
#include <hip/hip_runtime.h>

// GMP forward: out[b,j] = sum_i xc[j+i-7] * ( W0[i] + sum_m a*(w1 + a*(w2 + a*w3)) ),
// a = |xc[j+i+m-14]|.  B=64, T=16384, M=8, K=3. Weights real.
//
// R3: TLP push. Three structurally different compute bodies (R0/R1/R2) all
// measured ~27us kernel time vs a ~3us VALU floor -> stall-dominated, not
// throughput-dominated. Scale the only untouched axis: occupancy.
//   CHUNK 1024->512, 2 outputs/thread, grid 1024->2048 blocks,
//   __launch_bounds__(256,8) -> 8 waves/SIMD (32 waves/CU, was 16).
// Sliding register window kept from R2 (compile-time indices only, no scratch;
// 2 ds refills/iteration). FMA/output stays at the 208 algebraic minimum.

#define B_SZ 64
#define T_SZ 16384
#define CHUNK 512
#define HALO 14               // 2*(M-1)
#define WIN (CHUNK + HALO)    // 526

__global__ __launch_bounds__(256, 8) void gmp_kernel(const float* __restrict__ x,
                                                     const float* __restrict__ W,
                                                     float* __restrict__ out) {
    __shared__ float2 xs[WIN];   // xc window
    __shared__ float  as[WIN];   // |xc| window
    const int tid   = threadIdx.x;
    const int chunk = blockIdx.x & 31;   // T/CHUNK = 32 chunks per row
    const int b     = blockIdx.x >> 5;
    const int j0    = chunk * CHUNK;

    // Stage window [j0-14, j0+512) of row b; zero-pad g<0.
    for (int q = tid; q < WIN; q += 256) {
        const int g = j0 - HALO + q;
        float2 v = make_float2(0.f, 0.f);
        if (g >= 0) v = ((const float2*)x)[(size_t)b * T_SZ + g];
        xs[q] = v;
        as[q] = sqrtf(fmaf(v.x, v.x, v.y * v.y));
    }
    __syncthreads();

    // Each thread: outputs j = j0 + 2*tid + {0,1}.
    const int t2 = 2 * tid;

    // Sliding register window (compile-time indices only).
    float a0 = as[t2 + 0], a1 = as[t2 + 1], a2 = as[t2 + 2];
    float a3 = as[t2 + 3], a4 = as[t2 + 4], a5 = as[t2 + 5];
    float a6 = as[t2 + 6], a7 = as[t2 + 7], a8 = as[t2 + 8];
    float2 x0 = xs[t2 + 7], x1 = xs[t2 + 8];

    const float*  __restrict__ arefill = &as[t2 + 9];
    const float2* __restrict__ xrefill = &xs[t2 + 9];

    float ar0 = 0.f, ar1 = 0.f;
    float ai0 = 0.f, ai1 = 0.f;

#define STEP(W1, W2, W3, A0, A1)                                           \
    {                                                                      \
        const float w1_ = (W1), w2_ = (W2), w3_ = (W3);                    \
        float h;                                                           \
        h = fmaf(A0, w3_, w2_); h = fmaf(A0, h, w1_); c0 = fmaf(A0, h, c0);\
        h = fmaf(A1, w3_, w2_); h = fmaf(A1, h, w1_); c1 = fmaf(A1, h, c1);\
    }

#pragma unroll 1
    for (int i = 0; i < 8; ++i) {
        const float* __restrict__ wp = &W[i * 25];   // uniform -> s_loads

        const float w0 = wp[0];
        float c0 = w0, c1 = w0;

        STEP(wp[1],  wp[2],  wp[3],  a0, a1)   // m=0
        STEP(wp[4],  wp[5],  wp[6],  a1, a2)   // m=1
        STEP(wp[7],  wp[8],  wp[9],  a2, a3)   // m=2
        STEP(wp[10], wp[11], wp[12], a3, a4)   // m=3
        STEP(wp[13], wp[14], wp[15], a4, a5)   // m=4
        STEP(wp[16], wp[17], wp[18], a5, a6)   // m=5
        STEP(wp[19], wp[20], wp[21], a6, a7)   // m=6
        STEP(wp[22], wp[23], wp[24], a7, a8)   // m=7

        ar0 = fmaf(x0.x, c0, ar0); ai0 = fmaf(x0.y, c0, ai0);
        ar1 = fmaf(x1.x, c1, ar1); ai1 = fmaf(x1.y, c1, ai1);

        if (i < 7) {  // wave-uniform branch (scalar)
            a0 = a1; a1 = a2; a2 = a3; a3 = a4;
            a4 = a5; a5 = a6; a6 = a7; a7 = a8;
            a8 = arefill[i];
            x0 = x1;
            x1 = xrefill[i];
        }
    }
#undef STEP

    // Two consecutive complex outputs -> one 16B store.
    float4* op = (float4*)&out[2 * ((size_t)b * T_SZ + j0 + t2)];
    op[0] = make_float4(ar0, ai0, ar1, ai1);
}

extern "C" void kernel_launch(void* const* d_in, const int* in_sizes, int n_in,
                              void* d_out, int out_size, void* d_ws, size_t ws_size,
                              hipStream_t stream) {
    const float* x = (const float*)d_in[0];
    // d_in[1] is h_0 (unused)
    const float* W = (const float*)d_in[2];
    float* out = (float*)d_out;
    const int grid = B_SZ * (T_SZ / CHUNK);  // 2048 blocks
    gmp_kernel<<<dim3(grid), dim3(256), 0, stream>>>(x, W, out);
}